// Round 1
// baseline (10358.156 us; speedup 1.0000x reference)
//
#include <hip/hip_runtime.h>
#include <math.h>

#define D   512
#define H2  1024   // gate hidden = 2D
#define E   64
#define TOPK 8
#define F   2048   // expert hidden = 4D
#define TM  32     // tokens per expert-tile block
#define KC  32     // F-chunk

__device__ __forceinline__ float gelu_exact(float v) {
    return 0.5f * v * (1.0f + erff(v * 0.70710678118654752f));
}

__global__ void zero_kernel(float* __restrict__ out, int n_out,
                            float* __restrict__ usage, int* __restrict__ cnt) {
    int i = blockIdx.x * blockDim.x + threadIdx.x;
    if (i < n_out) out[i] = 0.0f;
    if (i < E) { usage[i] = 0.0f; cnt[i] = 0; }
}

__global__ __launch_bounds__(256) void gate_kernel(
    const float* __restrict__ x,
    const float* __restrict__ gw1, const float* __restrict__ gb1,
    const float* __restrict__ gw2, const float* __restrict__ gb2,
    float* __restrict__ usage, int* __restrict__ cnt,
    int* __restrict__ ptok, float* __restrict__ pw, int T)
{
    __shared__ float xs[D];
    __shared__ float hs[H2];
    const int t   = blockIdx.x;
    const int tid = threadIdx.x;

    const float* xrow = x + (size_t)t * D;
    xs[tid]       = xrow[tid];
    xs[tid + 256] = xrow[tid + 256];
    __syncthreads();

    // h = relu(x @ gw1 + gb1) ; each thread owns 4 columns (coalesced gw1)
    float acc0 = 0.f, acc1 = 0.f, acc2 = 0.f, acc3 = 0.f;
    for (int d = 0; d < D; ++d) {
        const float xv = xs[d];
        const float* wrow = gw1 + (size_t)d * H2 + tid;
        acc0 += xv * wrow[0];
        acc1 += xv * wrow[256];
        acc2 += xv * wrow[512];
        acc3 += xv * wrow[768];
    }
    hs[tid      ] = fmaxf(acc0 + gb1[tid      ], 0.f);
    hs[tid + 256] = fmaxf(acc1 + gb1[tid + 256], 0.f);
    hs[tid + 512] = fmaxf(acc2 + gb1[tid + 512], 0.f);
    hs[tid + 768] = fmaxf(acc3 + gb1[tid + 768], 0.f);
    __syncthreads();

    if (tid < E) {   // wave 0 only: logits, softmax, top-k
        float l = gb2[tid];
        for (int k = 0; k < H2; ++k)
            l += hs[k] * gw2[(size_t)k * E + tid];

        // softmax over the 64 lanes
        float mx = l;
        #pragma unroll
        for (int off = 32; off >= 1; off >>= 1) mx = fmaxf(mx, __shfl_xor(mx, off));
        float pv = expf(l - mx);
        float sm = pv;
        #pragma unroll
        for (int off = 32; off >= 1; off >>= 1) sm += __shfl_xor(sm, off);
        const float score = pv / sm;

        atomicAdd(&usage[tid], score);

        // iterative argmax top-8 (tie-break: lower index, matches lax.top_k)
        float v = score;
        float s8 = 0.f;
        float myw = 0.f; int mye = 0;
        #pragma unroll
        for (int i = 0; i < TOPK; ++i) {
            float bv = v; int bi = tid;
            #pragma unroll
            for (int off = 32; off >= 1; off >>= 1) {
                float ov = __shfl_xor(bv, off);
                int   oi = __shfl_xor(bi, off);
                if (ov > bv || (ov == bv && oi < bi)) { bv = ov; bi = oi; }
            }
            s8 += bv;
            if (tid == i)  { myw = bv; mye = bi; }   // lane i records i-th pick
            if (tid == bi) v = -1.0f;                // mask winner
        }
        if (tid < TOPK) {
            const float w = myw / s8;                // renormalized
            const int pos = atomicAdd(&cnt[mye], 1);
            ptok[(size_t)mye * T + pos] = t;
            pw  [(size_t)mye * T + pos] = w;
        }
    }
}

__global__ void lbloss_kernel(const float* __restrict__ usage,
                              float* __restrict__ out_loss, float invT) {
    const int tid = threadIdx.x;  // 64 threads
    const float u = usage[tid] * invT;
    const float d = u - (1.0f / 64.0f);
    float sq = d * d;
    #pragma unroll
    for (int off = 32; off >= 1; off >>= 1) sq += __shfl_xor(sq, off);
    if (tid == 0) *out_loss = 0.01f * (sq / 64.0f);
}

__global__ __launch_bounds__(256, 2) void expert_kernel(
    const float* __restrict__ x,
    const float* __restrict__ ew1, const float* __restrict__ eb1,
    const float* __restrict__ ew2, const float* __restrict__ eb2,
    const int* __restrict__ cnt, const int* __restrict__ ptok,
    const float* __restrict__ pw,
    float* __restrict__ out, int T)
{
    const int e = blockIdx.y;
    const int n = cnt[e];
    const int base = blockIdx.x * TM;
    if (base >= n) return;
    int m = n - base; if (m > TM) m = TM;

    __shared__ float Xs[TM][D + 4];   // stride 516: kills stride-512 bank aliasing
    __shared__ float Hs[TM][KC + 4];  // stride 36
    __shared__ int   toks[TM];
    __shared__ float wts[TM];

    const int tid = threadIdx.x;
    if (tid < TM) {
        if (tid < m) {
            toks[tid] = ptok[(size_t)e * T + base + tid];
            wts [tid] = pw  [(size_t)e * T + base + tid];
        } else { toks[tid] = 0; wts[tid] = 0.f; }
    }
    __syncthreads();

    for (int idx = tid; idx < TM * D; idx += 256) {
        const int tt = idx >> 9;          // /D
        const int dd = idx & (D - 1);
        Xs[tt][dd] = (tt < m) ? x[(size_t)toks[tt] * D + dd] : 0.f;
    }

    const float* w1e = ew1 + (size_t)e * D * F;
    const float* w2e = ew2 + (size_t)e * F * D;
    const float* b1e = eb1 + (size_t)e * F;
    const float* b2e = eb2 + (size_t)e * D;

    float y0[TM], y1[TM];
    #pragma unroll
    for (int i = 0; i < TM; ++i) { y0[i] = 0.f; y1[i] = 0.f; }

    const int tph = tid >> 3;            // phase-1 token  (0..31)
    const int jkb = (tid & 7) << 2;      // phase-1 col base (0,4,...,28)

    for (int kc = 0; kc < F; kc += KC) {
        __syncthreads();   // previous phase-2 done reading Hs
        // ---- phase 1: Hs[t][jk] = gelu(X @ W1 + b1) chunk ----
        {
            float a0 = 0.f, a1 = 0.f, a2 = 0.f, a3 = 0.f;
            const float* w1p = w1e + kc + jkb;
            #pragma unroll 4
            for (int d4 = 0; d4 < D / 4; ++d4) {
                const float4 xv  = *(const float4*)&Xs[tph][d4 * 4];
                const float4 wv0 = *(const float4*)&w1p[(size_t)(d4 * 4 + 0) * F];
                const float4 wv1 = *(const float4*)&w1p[(size_t)(d4 * 4 + 1) * F];
                const float4 wv2 = *(const float4*)&w1p[(size_t)(d4 * 4 + 2) * F];
                const float4 wv3 = *(const float4*)&w1p[(size_t)(d4 * 4 + 3) * F];
                a0 += xv.x * wv0.x + xv.y * wv1.x + xv.z * wv2.x + xv.w * wv3.x;
                a1 += xv.x * wv0.y + xv.y * wv1.y + xv.z * wv2.y + xv.w * wv3.y;
                a2 += xv.x * wv0.z + xv.y * wv1.z + xv.z * wv2.z + xv.w * wv3.z;
                a3 += xv.x * wv0.w + xv.y * wv1.w + xv.z * wv2.w + xv.w * wv3.w;
            }
            const float4 bb = *(const float4*)&b1e[kc + jkb];
            float4 g;
            g.x = gelu_exact(a0 + bb.x);
            g.y = gelu_exact(a1 + bb.y);
            g.z = gelu_exact(a2 + bb.z);
            g.w = gelu_exact(a3 + bb.w);
            *(float4*)&Hs[tph][jkb] = g;
        }
        __syncthreads();
        // ---- phase 2: y += Hs @ W2 chunk (W2 chunk in registers) ----
        {
            float w2r0[KC], w2r1[KC];
            #pragma unroll
            for (int k = 0; k < KC; ++k) {
                const float* w2row = w2e + (size_t)(kc + k) * D;
                w2r0[k] = w2row[tid];
                w2r1[k] = w2row[tid + 256];
            }
            #pragma unroll
            for (int t = 0; t < TM; ++t) {
                float s0 = y0[t], s1 = y1[t];
                #pragma unroll
                for (int kq = 0; kq < KC / 4; ++kq) {
                    const float4 h4 = *(const float4*)&Hs[t][kq * 4];
                    s0 += h4.x * w2r0[kq*4+0] + h4.y * w2r0[kq*4+1]
                        + h4.z * w2r0[kq*4+2] + h4.w * w2r0[kq*4+3];
                    s1 += h4.x * w2r1[kq*4+0] + h4.y * w2r1[kq*4+1]
                        + h4.z * w2r1[kq*4+2] + h4.w * w2r1[kq*4+3];
                }
                y0[t] = s0; y1[t] = s1;
            }
        }
    }

    // ---- epilogue: out[tok] += w * (y + b2)  (statically indexed, guarded) ----
    const float b2a = b2e[tid];
    const float b2b = b2e[tid + 256];
    #pragma unroll
    for (int t = 0; t < TM; ++t) {
        if (t < m) {
            const float w = wts[t];
            const size_t o = (size_t)toks[t] * D;
            atomicAdd(&out[o + tid      ], w * (y0[t] + b2a));
            atomicAdd(&out[o + tid + 256], w * (y1[t] + b2b));
        }
    }
}

extern "C" void kernel_launch(void* const* d_in, const int* in_sizes, int n_in,
                              void* d_out, int out_size, void* d_ws, size_t ws_size,
                              hipStream_t stream) {
    const float* x   = (const float*)d_in[0];
    const float* gw1 = (const float*)d_in[1];
    const float* gb1 = (const float*)d_in[2];
    const float* gw2 = (const float*)d_in[3];
    const float* gb2 = (const float*)d_in[4];
    const float* ew1 = (const float*)d_in[5];
    const float* eb1 = (const float*)d_in[6];
    const float* ew2 = (const float*)d_in[7];
    const float* eb2 = (const float*)d_in[8];
    float* out = (float*)d_out;

    const int T = in_sizes[0] / D;   // 2048

    // workspace layout (floats): usage[64] | cnt[64] | ptok[E*T] | pw[E*T]
    float* usage = (float*)d_ws;
    int*   cnt   = (int*)  ((char*)d_ws + (size_t)E * 4);
    int*   ptok  = (int*)  ((char*)d_ws + (size_t)2 * E * 4);
    float* pwv   = (float*)((char*)d_ws + ((size_t)2 * E + (size_t)E * T) * 4);

    zero_kernel<<<(out_size + 255) / 256, 256, 0, stream>>>(out, out_size, usage, cnt);

    gate_kernel<<<T, 256, 0, stream>>>(x, gw1, gb1, gw2, gb2,
                                       usage, cnt, ptok, pwv, T);

    lbloss_kernel<<<1, 64, 0, stream>>>(usage, out + (out_size - 1), 1.0f / (float)T);

    dim3 egrid((T + TM - 1) / TM, E);
    expert_kernel<<<egrid, 256, 0, stream>>>(x, ew1, eb1, ew2, eb2,
                                             cnt, ptok, pwv, out, T);
}